// Round 11
// baseline (460.117 us; speedup 1.0000x reference)
//
#include <hip/hip_runtime.h>
#include <hip/hip_fp16.h>

#define NLEV 8
#define BASE 512

typedef _Float16 h8 __attribute__((ext_vector_type(8)));
typedef float f4v __attribute__((ext_vector_type(4)));
typedef signed char c8 __attribute__((ext_vector_type(8)));

#define QSCALE 12700.0f

// byte offset of int8 mip level k inside qpyr (interleaved texels, 16 B each)
__host__ __device__ __forceinline__ long qoff(int k) {
    return (k == 0) ? 0L : (12582912L + 4194304L - (4194304L >> (2 * k - 2)));
}
#define QPYR_BYTES 16776960L
__host__ __device__ __forceinline__ long moff(int k) {
    return 4194304L - (4194304L >> (2 * k - 2));
}
#define MIPS_HALVES 4194048L
// ws layout: [qpyr 16.8MB][fp16 staging 8.4MB][counters 4KB][rec n*16][idx n*4]
#define CNT_OFF 25165056L
#define REC_OFF 25169152L

// -------- fused mip build + int8 quantize (interleaved layout, as R8/R9) ----
__global__ __launch_bounds__(256) void ds16_first(const float* __restrict__ src,
                                                  _Float16* __restrict__ dst,
                                                  signed char* __restrict__ qpyr, int r2) {
    int idx = blockIdx.x * blockDim.x + threadIdx.x;
    int total = 3 * r2 * r2 * 2;
    if (idx >= total) return;
    int g = idx & 1;
    int rest = idx >> 1;
    int u = rest % r2; rest /= r2;
    int v = rest % r2;
    int p = rest / r2;
    int rs = r2 * 2;
    const f4v* s4 = (const f4v*)src;
    long t00 = ((long)p * rs + 2 * v) * rs + 2 * u;
    long t01 = t00 + 1, t10 = t00 + rs, t11 = t10 + 1;
    f4v a0 = s4[t00 * 4 + g * 2], a1 = s4[t00 * 4 + g * 2 + 1];
    f4v b0 = s4[t01 * 4 + g * 2], b1 = s4[t01 * 4 + g * 2 + 1];
    f4v c0 = s4[t10 * 4 + g * 2], c1 = s4[t10 * 4 + g * 2 + 1];
    f4v d0 = s4[t11 * 4 + g * 2], d1 = s4[t11 * 4 + g * 2 + 1];
    h8 o;
    c8 qa, qb_, qc, qd, qo;
#pragma unroll
    for (int j = 0; j < 4; ++j) {
        float m0 = (a0[j] + b0[j] + c0[j] + d0[j]) * 0.25f;
        float m1 = (a1[j] + b1[j] + c1[j] + d1[j]) * 0.25f;
        o[j] = (_Float16)m0; o[4 + j] = (_Float16)m1;
        qo[j] = (signed char)(int)rintf(m0 * QSCALE);
        qo[4 + j] = (signed char)(int)rintf(m1 * QSCALE);
        qa[j] = (signed char)(int)rintf(a0[j] * QSCALE);  qa[4 + j] = (signed char)(int)rintf(a1[j] * QSCALE);
        qb_[j] = (signed char)(int)rintf(b0[j] * QSCALE); qb_[4 + j] = (signed char)(int)rintf(b1[j] * QSCALE);
        qc[j] = (signed char)(int)rintf(c0[j] * QSCALE);  qc[4 + j] = (signed char)(int)rintf(c1[j] * QSCALE);
        qd[j] = (signed char)(int)rintf(d0[j] * QSCALE);  qd[4 + j] = (signed char)(int)rintf(d1[j] * QSCALE);
    }
    ((h8*)dst)[idx] = o;
    *(c8*)(qpyr + t00 * 16 + g * 8) = qa;
    *(c8*)(qpyr + t01 * 16 + g * 8) = qb_;
    *(c8*)(qpyr + t10 * 16 + g * 8) = qc;
    *(c8*)(qpyr + t11 * 16 + g * 8) = qd;
    *(c8*)(qpyr + qoff(1) + (long)idx * 8) = qo;
}

__global__ __launch_bounds__(256) void ds16(const _Float16* __restrict__ src,
                                            _Float16* __restrict__ dst,
                                            signed char* __restrict__ qlvl, int r2) {
    int idx = blockIdx.x * blockDim.x + threadIdx.x;
    int total = 3 * r2 * r2 * 2;
    if (idx >= total) return;
    int g = idx & 1;
    int rest = idx >> 1;
    int u = rest % r2; rest /= r2;
    int v = rest % r2;
    int p = rest / r2;
    int rs = r2 * 2;
    const h8* s8 = (const h8*)src;
    long t00 = ((long)p * rs + 2 * v) * rs + 2 * u;
    long t01 = t00 + 1, t10 = t00 + rs, t11 = t10 + 1;
    h8 A = s8[t00 * 2 + g], B = s8[t01 * 2 + g], C = s8[t10 * 2 + g], D = s8[t11 * 2 + g];
    h8 o;
    c8 q;
#pragma unroll
    for (int j = 0; j < 8; ++j) {
        float m = ((float)A[j] + (float)B[j] + (float)C[j] + (float)D[j]) * 0.25f;
        o[j] = (_Float16)m;
        q[j] = (signed char)(int)rintf(m * QSCALE);
    }
    ((h8*)dst)[idx] = o;
    *(c8*)(qlvl + (long)idx * 8) = q;
}

// -------- counting sort by (l0, y-octant, z-octant): 512 buckets ------------
__device__ __forceinline__ int bkey(float y, float z, float lev) {
    int l0 = (int)floorf(lev);
    int yq = min(max((int)(y * 8.0f), 0), 7);
    int zq = min(max((int)(z * 8.0f), 0), 7);
    return (l0 << 6) | (yq << 3) | zq;
}

__global__ __launch_bounds__(256) void hist_k(const float* __restrict__ x,
                                              const float* __restrict__ level,
                                              int* __restrict__ hist, int n) {
    __shared__ int h[512];
    for (int i = threadIdx.x; i < 512; i += 256) h[i] = 0;
    __syncthreads();
    for (long i = (long)blockIdx.x * blockDim.x + threadIdx.x; i < n;
         i += (long)gridDim.x * blockDim.x) {
        float lev = fminf(fmaxf(level[i], 0.0f), (float)(NLEV - 1));
        atomicAdd(&h[bkey(x[3 * i + 1], x[3 * i + 2], lev)], 1);
    }
    __syncthreads();
    for (int i = threadIdx.x; i < 512; i += 256)
        if (h[i]) atomicAdd(&hist[i], h[i]);
}

__global__ __launch_bounds__(512) void scan512(const int* __restrict__ hist,
                                               int* __restrict__ ofs) {
    __shared__ int s[512];
    int t = threadIdx.x;
    int v0 = hist[t];
    s[t] = v0;
    __syncthreads();
    for (int off = 1; off < 512; off <<= 1) {
        int v = (t >= off) ? s[t - off] : 0;
        __syncthreads();
        s[t] += v;
        __syncthreads();
    }
    ofs[t] = s[t] - v0;   // exclusive prefix
}

__global__ __launch_bounds__(256) void scatter_k(const float* __restrict__ x,
                                                 const float* __restrict__ level,
                                                 int* __restrict__ ofs,
                                                 f4v* __restrict__ rec,
                                                 unsigned int* __restrict__ idx, int n) {
    long i = (long)blockIdx.x * blockDim.x + threadIdx.x;
    if (i >= n) return;
    float px = x[3 * i + 0], py = x[3 * i + 1], pz = x[3 * i + 2];
    float lev = fminf(fmaxf(level[i], 0.0f), (float)(NLEV - 1));
    int key = bkey(py, pz, lev);
    int pos = atomicAdd(&ofs[key], 1);
    f4v r = {px, py, pz, lev};
    rec[pos] = r;
    idx[pos] = (unsigned int)i;
}

// -------- sampler (R8 core): 4 lanes per point, optional sorted indirection -
template <bool SORTED>
__global__ __launch_bounds__(256) void tm_sample_q(const f4v* __restrict__ rec,
                                                   const unsigned int* __restrict__ idx,
                                                   const float* __restrict__ x,
                                                   const float* __restrict__ level,
                                                   const signed char* __restrict__ qpyr,
                                                   float* __restrict__ out, int n) {
    int t = blockIdx.x * blockDim.x + threadIdx.x;
    int j = t >> 2;
    if (j >= n) return;
    int fg = t & 1;
    int usel = (t >> 1) & 1;

    float px, py, pz, lev;
    long oi;
    if constexpr (SORTED) {
        f4v r = rec[j];
        px = r[0]; py = r[1]; pz = r[2]; lev = r[3];
        oi = idx[j];
    } else {
        px = x[3 * j + 0]; py = x[3 * j + 1]; pz = x[3 * j + 2];
        lev = fminf(fmaxf(level[j], 0.0f), (float)(NLEV - 1));
        oi = j;
    }
    float l0f = floorf(lev);
    float frac = lev - l0f;
    int l0 = (int)l0f;
    int k1 = min(l0 + 1, NLEV - 1);

    float uu[3] = {py, px, px};
    float vv[3] = {pz, pz, py};
    int rr[2] = {BASE >> l0, BASE >> k1};
    const signed char* qb[2] = {qpyr + qoff(l0), qpyr + qoff(k1)};
    const float QINV = 1.0f / QSCALE;
    float lw[2] = {(1.0f - frac) * QINV, frac * QINV};

    c8 tq[12];
    float wgt[12];

#pragma unroll
    for (int s = 0; s < 2; ++s) {
        int r = rr[s];
        float rf = (float)r;
#pragma unroll
        for (int p = 0; p < 3; ++p) {
            float cu = uu[p] * rf - 0.5f;
            float cv = vv[p] * rf - 0.5f;
            float fu0 = floorf(cu), fv0 = floorf(cv);
            float fu = cu - fu0, fv = cv - fv0;
            int iu0 = (int)fu0, iv0 = (int)fv0;
            int u0 = min(max(iu0, 0), r - 1);
            int u1 = min(max(iu0 + 1, 0), r - 1);
            int v0 = min(max(iv0, 0), r - 1);
            int v1 = min(max(iv0 + 1, 0), r - 1);
            int u_ = usel ? u1 : u0;
            float wu_ = usel ? fu : (1.0f - fu);
            long pb = (long)p * r * r;
            long b0 = (pb + (long)v0 * r + u_) * 16 + fg * 8;
            long b1 = (pb + (long)v1 * r + u_) * 16 + fg * 8;
            int id = s * 6 + p * 2;
            tq[id + 0] = *(const c8*)(qb[s] + b0);
            tq[id + 1] = *(const c8*)(qb[s] + b1);
            wgt[id + 0] = (1.0f - fv) * wu_ * lw[s];
            wgt[id + 1] = fv * wu_ * lw[s];
        }
    }

    float acc[3][8];
#pragma unroll
    for (int p = 0; p < 3; ++p)
#pragma unroll
        for (int j2 = 0; j2 < 8; ++j2) acc[p][j2] = 0.f;

#pragma unroll
    for (int s = 0; s < 2; ++s)
#pragma unroll
        for (int p = 0; p < 3; ++p) {
            int id = s * 6 + p * 2;
            float w0 = wgt[id + 0], w1 = wgt[id + 1];
#pragma unroll
            for (int j2 = 0; j2 < 8; ++j2)
                acc[p][j2] += (float)tq[id + 0][j2] * w0 + (float)tq[id + 1][j2] * w1;
        }

#pragma unroll
    for (int p = 0; p < 3; ++p)
#pragma unroll
        for (int j2 = 0; j2 < 8; ++j2)
            acc[p][j2] += __shfl_xor(acc[p][j2], 2, 64);

    f4v* o4 = (f4v*)out;
    long ob = oi * 12 + fg * 2;
    if (usel == 0) {
        f4v r0 = {acc[0][0], acc[0][1], acc[0][2], acc[0][3]};
        f4v r1 = {acc[0][4], acc[0][5], acc[0][6], acc[0][7]};
        f4v r4 = {acc[2][0], acc[2][1], acc[2][2], acc[2][3]};
        f4v r5 = {acc[2][4], acc[2][5], acc[2][6], acc[2][7]};
        o4[ob + 0] = r0;
        o4[ob + 1] = r1;
        o4[ob + 8] = r4;
        o4[ob + 9] = r5;
    } else {
        f4v r2 = {acc[1][0], acc[1][1], acc[1][2], acc[1][3]};
        f4v r3 = {acc[1][4], acc[1][5], acc[1][6], acc[1][7]};
        o4[ob + 4] = r2;
        o4[ob + 5] = r3;
    }
}

extern "C" void kernel_launch(void* const* d_in, const int* in_sizes, int n_in,
                              void* d_out, int out_size, void* d_ws, size_t ws_size,
                              hipStream_t stream) {
    const float* x     = (const float*)d_in[0];
    const float* level = (const float*)d_in[1];
    const float* tex   = (const float*)d_in[2];
    float* out = (float*)d_out;
    signed char* qpyr = (signed char*)d_ws;
    _Float16* wsh = (_Float16*)((char*)d_ws + QPYR_BYTES);
    int n = in_sizes[0] / 3;

    // fused mip build + int8 quantization
    {
        int r2 = BASE >> 1;
        int total = 3 * r2 * r2 * 2;
        ds16_first<<<(total + 255) / 256, 256, 0, stream>>>(tex, wsh + moff(1), qpyr, r2);
    }
    for (int k = 2; k < NLEV; ++k) {
        int r2 = BASE >> k;
        int total = 3 * r2 * r2 * 2;
        ds16<<<(total + 255) / 256, 256, 0, stream>>>(wsh + moff(k - 1), wsh + moff(k),
                                                      qpyr + qoff(k), r2);
    }

    bool sorted = ws_size >= (size_t)(REC_OFF + (long)n * 20);
    long tt = (long)n * 4;
    int sblocks = (int)((tt + 255) / 256);

    if (sorted) {
        int* hist = (int*)((char*)d_ws + CNT_OFF);
        int* ofs  = hist + 512;
        f4v* rec  = (f4v*)((char*)d_ws + REC_OFF);
        unsigned int* idx = (unsigned int*)((char*)d_ws + REC_OFF + (long)n * 16);
        hipMemsetAsync(hist, 0, 4096, stream);
        hist_k<<<1024, 256, 0, stream>>>(x, level, hist, n);
        scan512<<<1, 512, 0, stream>>>(hist, ofs);
        scatter_k<<<(n + 255) / 256, 256, 0, stream>>>(x, level, ofs, rec, idx, n);
        tm_sample_q<true><<<sblocks, 256, 0, stream>>>(rec, idx, x, level, qpyr, out, n);
    } else {
        tm_sample_q<false><<<sblocks, 256, 0, stream>>>(nullptr, nullptr, x, level, qpyr, out, n);
    }
}

// Round 12
// 162.206 us; speedup vs baseline: 2.8366x; 2.8366x over previous
//
#include <hip/hip_runtime.h>
#include <hip/hip_fp16.h>

#define NLEV 8
#define BASE 512

typedef _Float16 h8 __attribute__((ext_vector_type(8)));
typedef float f4v __attribute__((ext_vector_type(4)));
typedef signed char c8 __attribute__((ext_vector_type(8)));

#define QSCALE 12700.0f
#define NB 256          // sort blocks
#define NBUK 512        // buckets

// byte offset of int8 mip level k inside qpyr (interleaved texels, 16 B each)
__host__ __device__ __forceinline__ long qoff(int k) {
    return (k == 0) ? 0L : (12582912L + 4194304L - (4194304L >> (2 * k - 2)));
}
#define QPYR_BYTES 16776960L
__host__ __device__ __forceinline__ long moff(int k) {
    return 4194304L - (4194304L >> (2 * k - 2));
}
#define MIPS_HALVES 4194048L
// ws layout: [qpyr][fp16 staging][bh 512*256*4][totals 512*4][base 512*4][rec n*16][idx n*4]
#define BH_OFF   25165056L
#define TOT_OFF  25689344L
#define BASE_OFF 25691392L
#define REC_OFF  25693440L

// -------- fused mip build + int8 quantize (interleaved, proven in R8) -------
__global__ __launch_bounds__(256) void ds16_first(const float* __restrict__ src,
                                                  _Float16* __restrict__ dst,
                                                  signed char* __restrict__ qpyr, int r2) {
    int idx = blockIdx.x * blockDim.x + threadIdx.x;
    int total = 3 * r2 * r2 * 2;
    if (idx >= total) return;
    int g = idx & 1;
    int rest = idx >> 1;
    int u = rest % r2; rest /= r2;
    int v = rest % r2;
    int p = rest / r2;
    int rs = r2 * 2;
    const f4v* s4 = (const f4v*)src;
    long t00 = ((long)p * rs + 2 * v) * rs + 2 * u;
    long t01 = t00 + 1, t10 = t00 + rs, t11 = t10 + 1;
    f4v a0 = s4[t00 * 4 + g * 2], a1 = s4[t00 * 4 + g * 2 + 1];
    f4v b0 = s4[t01 * 4 + g * 2], b1 = s4[t01 * 4 + g * 2 + 1];
    f4v c0 = s4[t10 * 4 + g * 2], c1 = s4[t10 * 4 + g * 2 + 1];
    f4v d0 = s4[t11 * 4 + g * 2], d1 = s4[t11 * 4 + g * 2 + 1];
    h8 o;
    c8 qa, qb_, qc, qd, qo;
#pragma unroll
    for (int j = 0; j < 4; ++j) {
        float m0 = (a0[j] + b0[j] + c0[j] + d0[j]) * 0.25f;
        float m1 = (a1[j] + b1[j] + c1[j] + d1[j]) * 0.25f;
        o[j] = (_Float16)m0; o[4 + j] = (_Float16)m1;
        qo[j] = (signed char)(int)rintf(m0 * QSCALE);
        qo[4 + j] = (signed char)(int)rintf(m1 * QSCALE);
        qa[j] = (signed char)(int)rintf(a0[j] * QSCALE);  qa[4 + j] = (signed char)(int)rintf(a1[j] * QSCALE);
        qb_[j] = (signed char)(int)rintf(b0[j] * QSCALE); qb_[4 + j] = (signed char)(int)rintf(b1[j] * QSCALE);
        qc[j] = (signed char)(int)rintf(c0[j] * QSCALE);  qc[4 + j] = (signed char)(int)rintf(c1[j] * QSCALE);
        qd[j] = (signed char)(int)rintf(d0[j] * QSCALE);  qd[4 + j] = (signed char)(int)rintf(d1[j] * QSCALE);
    }
    ((h8*)dst)[idx] = o;
    *(c8*)(qpyr + t00 * 16 + g * 8) = qa;
    *(c8*)(qpyr + t01 * 16 + g * 8) = qb_;
    *(c8*)(qpyr + t10 * 16 + g * 8) = qc;
    *(c8*)(qpyr + t11 * 16 + g * 8) = qd;
    *(c8*)(qpyr + qoff(1) + (long)idx * 8) = qo;
}

__global__ __launch_bounds__(256) void ds16(const _Float16* __restrict__ src,
                                            _Float16* __restrict__ dst,
                                            signed char* __restrict__ qlvl, int r2) {
    int idx = blockIdx.x * blockDim.x + threadIdx.x;
    int total = 3 * r2 * r2 * 2;
    if (idx >= total) return;
    int g = idx & 1;
    int rest = idx >> 1;
    int u = rest % r2; rest /= r2;
    int v = rest % r2;
    int p = rest / r2;
    int rs = r2 * 2;
    const h8* s8 = (const h8*)src;
    long t00 = ((long)p * rs + 2 * v) * rs + 2 * u;
    long t01 = t00 + 1, t10 = t00 + rs, t11 = t10 + 1;
    h8 A = s8[t00 * 2 + g], B = s8[t01 * 2 + g], C = s8[t10 * 2 + g], D = s8[t11 * 2 + g];
    h8 o;
    c8 q;
#pragma unroll
    for (int j = 0; j < 8; ++j) {
        float m = ((float)A[j] + (float)B[j] + (float)C[j] + (float)D[j]) * 0.25f;
        o[j] = (_Float16)m;
        q[j] = (signed char)(int)rintf(m * QSCALE);
    }
    ((h8*)dst)[idx] = o;
    *(c8*)(qlvl + (long)idx * 8) = q;
}

// -------- contention-free counting sort by (l0, y-oct, z-oct) ---------------
__device__ __forceinline__ int bkey(float y, float z, float lev) {
    int l0 = (int)floorf(lev);
    int yq = min(max((int)(y * 8.0f), 0), 7);
    int zq = min(max((int)(z * 8.0f), 0), 7);
    return (l0 << 6) | (yq << 3) | zq;
}

// per-block histograms -> bh[bucket*NB + block]
__global__ __launch_bounds__(256) void hist2(const float* __restrict__ x,
                                             const float* __restrict__ level,
                                             int* __restrict__ bh, int n, int chunk) {
    __shared__ int h[NBUK];
    for (int k = threadIdx.x; k < NBUK; k += 256) h[k] = 0;
    __syncthreads();
    long start = (long)blockIdx.x * chunk;
    long end = min((long)n, start + chunk);
    for (long i = start + threadIdx.x; i < end; i += 256) {
        float lev = fminf(fmaxf(level[i], 0.0f), (float)(NLEV - 1));
        atomicAdd(&h[bkey(x[3 * i + 1], x[3 * i + 2], lev)], 1);
    }
    __syncthreads();
    for (int k = threadIdx.x; k < NBUK; k += 256)
        bh[k * NB + blockIdx.x] = h[k];
}

// per-bucket exclusive scan over its NB block-counts; emit totals
__global__ __launch_bounds__(NB) void scanA(int* __restrict__ bh, int* __restrict__ totals) {
    __shared__ int s[NB];
    int bucket = blockIdx.x;
    int t = threadIdx.x;
    int v0 = bh[bucket * NB + t];
    s[t] = v0;
    __syncthreads();
    for (int off = 1; off < NB; off <<= 1) {
        int v = (t >= off) ? s[t - off] : 0;
        __syncthreads();
        s[t] += v;
        __syncthreads();
    }
    bh[bucket * NB + t] = s[t] - v0;          // exclusive within bucket
    if (t == NB - 1) totals[bucket] = s[t];
}

// exclusive scan of the 512 bucket totals -> base
__global__ __launch_bounds__(NBUK) void scan512(const int* __restrict__ totals,
                                                int* __restrict__ base) {
    __shared__ int s[NBUK];
    int t = threadIdx.x;
    int v0 = totals[t];
    s[t] = v0;
    __syncthreads();
    for (int off = 1; off < NBUK; off <<= 1) {
        int v = (t >= off) ? s[t - off] : 0;
        __syncthreads();
        s[t] += v;
        __syncthreads();
    }
    base[t] = s[t] - v0;
}

// scatter with LDS-only atomics: pos = base[k] + bh[k][block] + local_rank
__global__ __launch_bounds__(256) void scatter2(const float* __restrict__ x,
                                                const float* __restrict__ level,
                                                const int* __restrict__ bh,
                                                const int* __restrict__ base,
                                                f4v* __restrict__ rec,
                                                unsigned int* __restrict__ idx,
                                                int n, int chunk) {
    __shared__ int lofs[NBUK];
    for (int k = threadIdx.x; k < NBUK; k += 256) lofs[k] = 0;
    __syncthreads();
    int b = blockIdx.x;
    long start = (long)b * chunk;
    long end = min((long)n, start + chunk);
    for (long i = start + threadIdx.x; i < end; i += 256) {
        float px = x[3 * i + 0], py = x[3 * i + 1], pz = x[3 * i + 2];
        float lev = fminf(fmaxf(level[i], 0.0f), (float)(NLEV - 1));
        int key = bkey(py, pz, lev);
        int lr = atomicAdd(&lofs[key], 1);
        int pos = base[key] + bh[key * NB + b] + lr;
        f4v r = {px, py, pz, lev};
        rec[pos] = r;
        idx[pos] = (unsigned int)i;
    }
}

// -------- sampler (R8 core): 4 lanes/point, sorted indirection, XCD swizzle -
template <bool SORTED>
__global__ __launch_bounds__(256) void tm_sample_q(const f4v* __restrict__ rec,
                                                   const unsigned int* __restrict__ idx,
                                                   const float* __restrict__ x,
                                                   const float* __restrict__ level,
                                                   const signed char* __restrict__ qpyr,
                                                   float* __restrict__ out, int n) {
    // bijective XCD swizzle (m204): consecutive work -> same XCD
    int nwg = gridDim.x;
    int q = nwg >> 3, r = nwg & 7;
    int xcd = blockIdx.x & 7;
    int sub = blockIdx.x >> 3;
    int wg = (xcd < r ? xcd * (q + 1) : r * (q + 1) + (xcd - r) * q) + sub;

    int t = wg * 256 + threadIdx.x;
    int j = t >> 2;
    if (j >= n) return;
    int fg = t & 1;
    int usel = (t >> 1) & 1;

    float px, py, pz, lev;
    long oi;
    if constexpr (SORTED) {
        f4v rr_ = rec[j];
        px = rr_[0]; py = rr_[1]; pz = rr_[2]; lev = rr_[3];
        oi = idx[j];
    } else {
        px = x[3 * j + 0]; py = x[3 * j + 1]; pz = x[3 * j + 2];
        lev = fminf(fmaxf(level[j], 0.0f), (float)(NLEV - 1));
        oi = j;
    }
    float l0f = floorf(lev);
    float frac = lev - l0f;
    int l0 = (int)l0f;
    int k1 = min(l0 + 1, NLEV - 1);

    float uu[3] = {py, px, px};
    float vv[3] = {pz, pz, py};
    int rr[2] = {BASE >> l0, BASE >> k1};
    const signed char* qb[2] = {qpyr + qoff(l0), qpyr + qoff(k1)};
    const float QINV = 1.0f / QSCALE;
    float lw[2] = {(1.0f - frac) * QINV, frac * QINV};

    c8 tq[12];
    float wgt[12];

#pragma unroll
    for (int s = 0; s < 2; ++s) {
        int r_ = rr[s];
        float rf = (float)r_;
#pragma unroll
        for (int p = 0; p < 3; ++p) {
            float cu = uu[p] * rf - 0.5f;
            float cv = vv[p] * rf - 0.5f;
            float fu0 = floorf(cu), fv0 = floorf(cv);
            float fu = cu - fu0, fv = cv - fv0;
            int iu0 = (int)fu0, iv0 = (int)fv0;
            int u0 = min(max(iu0, 0), r_ - 1);
            int u1 = min(max(iu0 + 1, 0), r_ - 1);
            int v0 = min(max(iv0, 0), r_ - 1);
            int v1 = min(max(iv0 + 1, 0), r_ - 1);
            int u_ = usel ? u1 : u0;
            float wu_ = usel ? fu : (1.0f - fu);
            long pb = (long)p * r_ * r_;
            long b0 = (pb + (long)v0 * r_ + u_) * 16 + fg * 8;
            long b1 = (pb + (long)v1 * r_ + u_) * 16 + fg * 8;
            int id = s * 6 + p * 2;
            tq[id + 0] = *(const c8*)(qb[s] + b0);
            tq[id + 1] = *(const c8*)(qb[s] + b1);
            wgt[id + 0] = (1.0f - fv) * wu_ * lw[s];
            wgt[id + 1] = fv * wu_ * lw[s];
        }
    }

    float acc[3][8];
#pragma unroll
    for (int p = 0; p < 3; ++p)
#pragma unroll
        for (int j2 = 0; j2 < 8; ++j2) acc[p][j2] = 0.f;

#pragma unroll
    for (int s = 0; s < 2; ++s)
#pragma unroll
        for (int p = 0; p < 3; ++p) {
            int id = s * 6 + p * 2;
            float w0 = wgt[id + 0], w1 = wgt[id + 1];
#pragma unroll
            for (int j2 = 0; j2 < 8; ++j2)
                acc[p][j2] += (float)tq[id + 0][j2] * w0 + (float)tq[id + 1][j2] * w1;
        }

#pragma unroll
    for (int p = 0; p < 3; ++p)
#pragma unroll
        for (int j2 = 0; j2 < 8; ++j2)
            acc[p][j2] += __shfl_xor(acc[p][j2], 2, 64);

    f4v* o4 = (f4v*)out;
    long ob = oi * 12 + fg * 2;
    if (usel == 0) {
        f4v r0 = {acc[0][0], acc[0][1], acc[0][2], acc[0][3]};
        f4v r1 = {acc[0][4], acc[0][5], acc[0][6], acc[0][7]};
        f4v r4 = {acc[2][0], acc[2][1], acc[2][2], acc[2][3]};
        f4v r5 = {acc[2][4], acc[2][5], acc[2][6], acc[2][7]};
        o4[ob + 0] = r0;
        o4[ob + 1] = r1;
        o4[ob + 8] = r4;
        o4[ob + 9] = r5;
    } else {
        f4v r2 = {acc[1][0], acc[1][1], acc[1][2], acc[1][3]};
        f4v r3 = {acc[1][4], acc[1][5], acc[1][6], acc[1][7]};
        o4[ob + 4] = r2;
        o4[ob + 5] = r3;
    }
}

extern "C" void kernel_launch(void* const* d_in, const int* in_sizes, int n_in,
                              void* d_out, int out_size, void* d_ws, size_t ws_size,
                              hipStream_t stream) {
    const float* x     = (const float*)d_in[0];
    const float* level = (const float*)d_in[1];
    const float* tex   = (const float*)d_in[2];
    float* out = (float*)d_out;
    signed char* qpyr = (signed char*)d_ws;
    _Float16* wsh = (_Float16*)((char*)d_ws + QPYR_BYTES);
    int n = in_sizes[0] / 3;

    // fused mip build + int8 quantization
    {
        int r2 = BASE >> 1;
        int total = 3 * r2 * r2 * 2;
        ds16_first<<<(total + 255) / 256, 256, 0, stream>>>(tex, wsh + moff(1), qpyr, r2);
    }
    for (int k = 2; k < NLEV; ++k) {
        int r2 = BASE >> k;
        int total = 3 * r2 * r2 * 2;
        ds16<<<(total + 255) / 256, 256, 0, stream>>>(wsh + moff(k - 1), wsh + moff(k),
                                                      qpyr + qoff(k), r2);
    }

    bool sorted = ws_size >= (size_t)(REC_OFF + (long)n * 20);
    long tt = (long)n * 4;
    int sblocks = (int)((tt + 255) / 256);

    if (sorted) {
        int* bh    = (int*)((char*)d_ws + BH_OFF);
        int* tot   = (int*)((char*)d_ws + TOT_OFF);
        int* base  = (int*)((char*)d_ws + BASE_OFF);
        f4v* rec   = (f4v*)((char*)d_ws + REC_OFF);
        unsigned int* idx = (unsigned int*)((char*)d_ws + REC_OFF + (long)n * 16);
        int chunk = (n + NB - 1) / NB;
        hist2<<<NB, 256, 0, stream>>>(x, level, bh, n, chunk);
        scanA<<<NBUK, NB, 0, stream>>>(bh, tot);
        scan512<<<1, NBUK, 0, stream>>>(tot, base);
        scatter2<<<NB, 256, 0, stream>>>(x, level, bh, base, rec, idx, n, chunk);
        tm_sample_q<true><<<sblocks, 256, 0, stream>>>(rec, idx, x, level, qpyr, out, n);
    } else {
        tm_sample_q<false><<<sblocks, 256, 0, stream>>>(nullptr, nullptr, x, level, qpyr, out, n);
    }
}